// Round 5
// baseline (2004.553 us; speedup 1.0000x reference)
//
#include <hip/hip_runtime.h>

typedef unsigned int uint;

// ---------- bf16 helpers ----------
__device__ __forceinline__ uint bfpack(float a, float b) {
  uint ua = __float_as_uint(a), ub = __float_as_uint(b);
  ua += 0x7fffu + ((ua >> 16) & 1u);   // RNE to bf16
  ub += 0x7fffu + ((ub >> 16) & 1u);
  return (ua >> 16) | (ub & 0xffff0000u);
}
__device__ __forceinline__ float bflo(uint d) { return __uint_as_float(d << 16); }
__device__ __forceinline__ float bfhi(uint d) { return __uint_as_float(d & 0xffff0000u); }

#if __has_builtin(__builtin_amdgcn_fdot2_f32_bf16)
#define HAVE_BFDOT 1
typedef __bf16 v2bf __attribute__((ext_vector_type(2)));
__device__ __forceinline__ float dot2bf(uint a, uint b, float c) {
  return __builtin_amdgcn_fdot2_f32_bf16(__builtin_bit_cast(v2bf, a),
                                         __builtin_bit_cast(v2bf, b), c, false);
}
#else
#define HAVE_BFDOT 0
#endif

// ---------- K1: transition table ----------
// Tcol[c*64 + j] = bf16x2( exp(tran[2j][c]), exp(tran[2j+1][c]) ), tran = log_softmax rows
__global__ void k_tran(const float* __restrict__ w, uint* __restrict__ Tcol) {
  __shared__ float rowLSE[128];
  int tid = threadIdx.x;                       // 128 threads
  const float4* w4 = (const float4*)(w + tid * 128);
  float se = 0.f;
  #pragma unroll 8
  for (int i = 0; i < 32; ++i) {
    float4 v = w4[i];
    se += __expf(v.x) + __expf(v.y) + __expf(v.z) + __expf(v.w);
  }
  rowLSE[tid] = __logf(se);                    // logits in (-1,1): shift-free LSE is fine
  __syncthreads();
  int c = tid;
  for (int j = 0; j < 64; ++j) {
    float a = __expf(w[(2 * j) * 128 + c]     - rowLSE[2 * j]);
    float b = __expf(w[(2 * j + 1) * 128 + c] - rowLSE[2 * j + 1]);
    Tcol[c * 64 + j] = bfpack(a, b);
  }
}

// ---------- K2a: logits (bf16, pair layout) + per-k sum of exp(logit) ----------
__global__ __launch_bounds__(256) void k_logits(const float* __restrict__ emb,
    const float* __restrict__ vocab, uint* __restrict__ qtbl,
    float* __restrict__ S_glob, int V) {
  __shared__ float S_part[128];
  int tid = threadIdx.x;
  int kt = tid & 15, vt = tid >> 4;
  int k0 = kt * 8;
  int vbase = blockIdx.x * 64 + vt * 4;
  if (tid < 128) S_part[tid] = 0.f;
  __syncthreads();

  float acc[4][8];
  #pragma unroll
  for (int i = 0; i < 4; ++i)
    #pragma unroll
    for (int r = 0; r < 8; ++r) acc[i][r] = 0.f;

  int vidx[4];
  #pragma unroll
  for (int i = 0; i < 4; ++i) { int vv = vbase + i; vidx[i] = (vv < V) ? vv : (V - 1); }

  const float4* emb4 = (const float4*)emb;
  const float4* voc4 = (const float4*)vocab;
  for (int jb = 0; jb < 32; ++jb) {
    float4 e4[8];
    #pragma unroll
    for (int r = 0; r < 8; ++r) e4[r] = emb4[(k0 + r) * 32 + jb];
    #pragma unroll
    for (int i = 0; i < 4; ++i) {
      float4 va = voc4[(size_t)vidx[i] * 32 + jb];
      #pragma unroll
      for (int r = 0; r < 8; ++r)
        acc[i][r] += va.x * e4[r].x + va.y * e4[r].y + va.z * e4[r].z + va.w * e4[r].w;
    }
  }

  float sume[8];
  #pragma unroll
  for (int r = 0; r < 8; ++r) sume[r] = 0.f;
  #pragma unroll
  for (int i = 0; i < 4; ++i) {
    int vv = vbase + i;
    if (vv < V) {
      #pragma unroll
      for (int r = 0; r < 8; ++r) sume[r] += __expf(acc[i][r]);   // |logit| <~ 40 : safe
      uint4 st;
      st.x = bfpack(acc[i][0], acc[i][1]);
      st.y = bfpack(acc[i][2], acc[i][3]);
      st.z = bfpack(acc[i][4], acc[i][5]);
      st.w = bfpack(acc[i][6], acc[i][7]);
      *((uint4*)(qtbl + (size_t)vv * 64) + kt) = st;
    }
  }
  #pragma unroll
  for (int r = 0; r < 8; ++r) atomicAdd(&S_part[k0 + r], sume[r]);
  __syncthreads();
  if (tid < 128) atomicAdd(&S_glob[tid], S_part[tid]);
}

// ---------- K2c: in-place q[v][k] = exp(emis - Emax_v) (bf16), Emax table ----------
__global__ __launch_bounds__(256) void k_qtab(uint* __restrict__ qtbl,
    const float* __restrict__ S_glob, float* __restrict__ Emax, int V) {
  int tid = threadIdx.x;
  int l = tid & 63;
  int v = blockIdx.x * 4 + (tid >> 6);
  if (v >= V) return;
  float2 S2 = ((const float2*)S_glob)[l];
  float z0 = __logf(S2.x), z1 = __logf(S2.y);
  size_t off = (size_t)v * 64 + l;
  uint d = qtbl[off];
  float e0 = bflo(d) - z0, e1 = bfhi(d) - z1;
  float m = fmaxf(e0, e1);
  #pragma unroll
  for (int s = 1; s < 64; s <<= 1) m = fmaxf(m, __shfl_xor(m, s, 64));
  float q0 = __expf(e0 - m), q1 = __expf(e1 - m);
  qtbl[off] = bfpack(q0, q1);
  if (l == 0) Emax[v] = m;
}

// ---------- K3: sequential scan. ONE wave per chain, zero memory on critical path. ----------
// Lane l holds output columns 2l,2l+1 of T (128 dwords, PINNED in VGPRs via asm) and
// the packed state u(2l,2l+1) in one VGPR. u broadcast via v_readlane (lane j's ud is
// exactly the input-pair dword j). No LDS, no barriers, no ds_read latency: the
// critical path is ud -> readlane -> v_dot2 -> ud, all VALU.

#define RL(j) ((uint)__builtin_amdgcn_readlane((int)ud, (j)))

#if HAVE_BFDOT
#define DOT4(i) { \
  uint u_0 = RL(4*(i)), u_1 = RL(4*(i)+1), u_2 = RL(4*(i)+2), u_3 = RL(4*(i)+3); \
  A0 = dot2bf(u_0, ta##i.x, A0); B0 = dot2bf(u_0, tb##i.x, B0); \
  A1 = dot2bf(u_1, ta##i.y, A1); B1 = dot2bf(u_1, tb##i.y, B1); \
  A2 = dot2bf(u_2, ta##i.z, A2); B2 = dot2bf(u_2, tb##i.z, B2); \
  A3 = dot2bf(u_3, ta##i.w, A3); B3 = dot2bf(u_3, tb##i.w, B3); }
#else
#define DOT4(i) { \
  uint u_0 = RL(4*(i)), u_1 = RL(4*(i)+1), u_2 = RL(4*(i)+2), u_3 = RL(4*(i)+3); \
  A0 = fmaf(bflo(u_0), bflo(ta##i.x), A0); A0 = fmaf(bfhi(u_0), bfhi(ta##i.x), A0); \
  B0 = fmaf(bflo(u_0), bflo(tb##i.x), B0); B0 = fmaf(bfhi(u_0), bfhi(tb##i.x), B0); \
  A1 = fmaf(bflo(u_1), bflo(ta##i.y), A1); A1 = fmaf(bfhi(u_1), bfhi(ta##i.y), A1); \
  B1 = fmaf(bflo(u_1), bflo(tb##i.y), B1); B1 = fmaf(bfhi(u_1), bfhi(tb##i.y), B1); \
  A2 = fmaf(bflo(u_2), bflo(ta##i.z), A2); A2 = fmaf(bfhi(u_2), bfhi(ta##i.z), A2); \
  B2 = fmaf(bflo(u_2), bflo(tb##i.z), B2); B2 = fmaf(bfhi(u_2), bfhi(tb##i.z), B2); \
  A3 = fmaf(bflo(u_3), bflo(ta##i.w), A3); A3 = fmaf(bfhi(u_3), bfhi(ta##i.w), A3); \
  B3 = fmaf(bflo(u_3), bflo(tb##i.w), B3); B3 = fmaf(bfhi(u_3), bfhi(tb##i.w), B3); }
#endif

#define REP16(M) M(0) M(1) M(2) M(3) M(4) M(5) M(6) M(7) \
                 M(8) M(9) M(10) M(11) M(12) M(13) M(14) M(15)

#define DECL_T(i) uint4 ta##i, tb##i;
#define LOAD_T(i) ta##i = ca[i]; tb##i = cb[i];
// Pin: kills global-load rematerialization (the R2/R3 failure mode).
#define PIN_T(i)  asm volatile("" : "+v"(ta##i.x), "+v"(ta##i.y), "+v"(ta##i.z), "+v"(ta##i.w)); \
                  asm volatile("" : "+v"(tb##i.x), "+v"(tb##i.y), "+v"(tb##i.z), "+v"(tb##i.w));

#define STEP(j) { \
  float A0 = 0.f, A1 = 0.f, A2 = 0.f, A3 = 0.f; \
  float B0 = 0.f, B1 = 0.f, B2 = 0.f, B3 = 0.f; \
  REP16(DOT4) \
  float s0 = (A0 + A1) + (A2 + A3); \
  float s1 = (B0 + B1) + (B2 + B3); \
  float nu0 = s0 * bflo(qc##j), nu1 = s1 * bfhi(qc##j); \
  { int tok = xrow[(tbase + (j) + 8) & 4095]; qc##j = qtbl[(size_t)tok * 64 + l]; } \
  if ((j) == 7) {                                 /* exact renorm every 8 steps */ \
    float tt = nu0 + nu1; \
    for (int s = 1; s < 64; s <<= 1) tt += __shfl_xor(tt, s, 64); \
    LLacc += __logf(tt); \
    float it = 1.0f / tt; nu0 *= it; nu1 *= it; \
  } \
  ud = bfpack(nu0, nu1); }

__global__ __launch_bounds__(64, 1) void k_chain(const int* __restrict__ x,
    const float* __restrict__ start_w, const float* __restrict__ start_b,
    const uint* __restrict__ Tcol, const uint* __restrict__ qtbl,
    float* __restrict__ chainLL) {
  int n = blockIdx.x, l = threadIdx.x;
  const int* xrow = x + (size_t)n * 4096;

  // full table fragment: columns 2l, 2l+1, all 64 input pairs
  const uint4* ca = (const uint4*)(Tcol + (2 * l) * 64);
  const uint4* cb = (const uint4*)(Tcol + (2 * l + 1) * 64);
  REP16(DECL_T)
  REP16(LOAD_T)
  REP16(PIN_T)

  // init: u0 = softmax(start_w + start_b), LL0 = LSE(alpha0)
  float a0i = start_w[2 * l] + start_b[2 * l];
  float a1i = start_w[2 * l + 1] + start_b[2 * l + 1];
  float m = fmaxf(a0i, a1i);
  #pragma unroll
  for (int s = 1; s < 64; s <<= 1) m = fmaxf(m, __shfl_xor(m, s, 64));
  float p0 = __expf(a0i - m), p1 = __expf(a1i - m);
  float tot = p0 + p1;
  #pragma unroll
  for (int s = 1; s < 64; s <<= 1) tot += __shfl_xor(tot, s, 64);
  float LLacc = m + __logf(tot);
  float inv = 1.0f / tot;
  uint ud = bfpack(p0 * inv, p1 * inv);           // packed u(2l,2l+1)

  uint qc0 = qtbl[(size_t)xrow[0] * 64 + l], qc1 = qtbl[(size_t)xrow[1] * 64 + l];
  uint qc2 = qtbl[(size_t)xrow[2] * 64 + l], qc3 = qtbl[(size_t)xrow[3] * 64 + l];
  uint qc4 = qtbl[(size_t)xrow[4] * 64 + l], qc5 = qtbl[(size_t)xrow[5] * 64 + l];
  uint qc6 = qtbl[(size_t)xrow[6] * 64 + l], qc7 = qtbl[(size_t)xrow[7] * 64 + l];

  for (int t8 = 0; t8 < 512; ++t8) {
    int tbase = t8 * 8;
    STEP(0) STEP(1) STEP(2) STEP(3) STEP(4) STEP(5) STEP(6) STEP(7)
  }
  if (l == 0) chainLL[n] = LLacc;
}

// ---------- K4a: sum of Emax over all tokens ----------
__global__ __launch_bounds__(256) void k_emaxsum(const int* __restrict__ x,
    const float* __restrict__ Emax, float* __restrict__ sumE, int NT) {
  int idx = blockIdx.x * 256 + threadIdx.x;
  float s = 0.f;
  for (; idx < NT; idx += 128 * 256) s += Emax[x[idx]];
  #pragma unroll
  for (int mk = 1; mk < 64; mk <<= 1) s += __shfl_xor(s, mk, 64);
  if ((threadIdx.x & 63) == 0) atomicAdd(sumE, s);
}

// ---------- K4b: final scalar ----------
__global__ void k_final(const float* __restrict__ chainLL, const float* __restrict__ sumE,
                        float* __restrict__ out, int N) {
  int l = threadIdx.x;
  float v = (l < N) ? chainLL[l] : 0.f;
  #pragma unroll
  for (int mk = 1; mk < 64; mk <<= 1) v += __shfl_xor(v, mk, 64);
  if (l == 0) out[0] = -(v + sumE[0]) / (float)N;
}

extern "C" void kernel_launch(void* const* d_in, const int* in_sizes, int n_in,
                              void* d_out, int out_size, void* d_ws, size_t ws_size,
                              hipStream_t stream) {
  if (n_in < 6) return;
  const int*   x       = (const int*)d_in[0];
  const float* start_w = (const float*)d_in[1];
  const float* start_b = (const float*)d_in[2];
  const float* trans_w = (const float*)d_in[3];
  const float* emb_w   = (const float*)d_in[4];
  const float* vocab_w = (const float*)d_in[5];
  int NT = in_sizes[0];
  int N  = NT / 4096;
  int V  = in_sizes[5] / 128;

  char* ws = (char*)d_ws;
  float* S_glob  = (float*)(ws + 0);        // 128 f
  float* sumE    = (float*)(ws + 512);      // 1 f
  float* chainLL = (float*)(ws + 768);      // N f
  uint*  Tcol    = (uint*)(ws + 1024);      // 128*64 dwords = 32 KB
  float* Emax    = (float*)(ws + 36864);    // V floats
  uint*  qtbl    = (uint*)(ws + 262144);    // V*64 dwords = 12.8 MB

  hipMemsetAsync(d_ws, 0, 1024, stream);
  k_tran<<<dim3(1), dim3(128), 0, stream>>>(trans_w, Tcol);
  k_logits<<<dim3((V + 63) / 64), dim3(256), 0, stream>>>(emb_w, vocab_w, qtbl, S_glob, V);
  k_qtab<<<dim3((V + 3) / 4), dim3(256), 0, stream>>>(qtbl, S_glob, Emax, V);
  k_chain<<<dim3(N), dim3(64), 0, stream>>>(x, start_w, start_b, Tcol, qtbl, chainLL);
  k_emaxsum<<<dim3(128), dim3(256), 0, stream>>>(x, Emax, sumE, NT);
  k_final<<<dim3(1), dim3(64), 0, stream>>>(chainLL, sumE, (float*)d_out, N);
}

// Round 6
// 1965.893 us; speedup vs baseline: 1.0197x; 1.0197x over previous
//
#include <hip/hip_runtime.h>

typedef unsigned int uint;

// ---------- bf16 helpers ----------
__device__ __forceinline__ uint bfpack(float a, float b) {
  uint ua = __float_as_uint(a), ub = __float_as_uint(b);
  ua += 0x7fffu + ((ua >> 16) & 1u);   // RNE to bf16
  ub += 0x7fffu + ((ub >> 16) & 1u);
  return (ua >> 16) | (ub & 0xffff0000u);
}
__device__ __forceinline__ float bflo(uint d) { return __uint_as_float(d << 16); }
__device__ __forceinline__ float bfhi(uint d) { return __uint_as_float(d & 0xffff0000u); }

#if __has_builtin(__builtin_amdgcn_fdot2_f32_bf16)
#define HAVE_BFDOT 1
typedef __bf16 v2bf __attribute__((ext_vector_type(2)));
__device__ __forceinline__ float dot2bf(uint a, uint b, float c) {
  return __builtin_amdgcn_fdot2_f32_bf16(__builtin_bit_cast(v2bf, a),
                                         __builtin_bit_cast(v2bf, b), c, false);
}
#else
#define HAVE_BFDOT 0
#endif

// ---------- K1: transition table ----------
// Tcol[c*64 + j] = bf16x2( exp(tran[2j][c]), exp(tran[2j+1][c]) ), tran = log_softmax rows
__global__ void k_tran(const float* __restrict__ w, uint* __restrict__ Tcol) {
  __shared__ float rowLSE[128];
  int tid = threadIdx.x;                       // 128 threads
  const float4* w4 = (const float4*)(w + tid * 128);
  float se = 0.f;
  #pragma unroll 8
  for (int i = 0; i < 32; ++i) {
    float4 v = w4[i];
    se += __expf(v.x) + __expf(v.y) + __expf(v.z) + __expf(v.w);
  }
  rowLSE[tid] = __logf(se);                    // logits in (-1,1): shift-free LSE is fine
  __syncthreads();
  int c = tid;
  for (int j = 0; j < 64; ++j) {
    float a = __expf(w[(2 * j) * 128 + c]     - rowLSE[2 * j]);
    float b = __expf(w[(2 * j + 1) * 128 + c] - rowLSE[2 * j + 1]);
    Tcol[c * 64 + j] = bfpack(a, b);
  }
}

// ---------- K2a: logits (bf16, pair layout) + per-k sum of exp(logit) ----------
__global__ __launch_bounds__(256) void k_logits(const float* __restrict__ emb,
    const float* __restrict__ vocab, uint* __restrict__ qtbl,
    float* __restrict__ S_glob, int V) {
  __shared__ float S_part[128];
  int tid = threadIdx.x;
  int kt = tid & 15, vt = tid >> 4;
  int k0 = kt * 8;
  int vbase = blockIdx.x * 64 + vt * 4;
  if (tid < 128) S_part[tid] = 0.f;
  __syncthreads();

  float acc[4][8];
  #pragma unroll
  for (int i = 0; i < 4; ++i)
    #pragma unroll
    for (int r = 0; r < 8; ++r) acc[i][r] = 0.f;

  int vidx[4];
  #pragma unroll
  for (int i = 0; i < 4; ++i) { int vv = vbase + i; vidx[i] = (vv < V) ? vv : (V - 1); }

  const float4* emb4 = (const float4*)emb;
  const float4* voc4 = (const float4*)vocab;
  for (int jb = 0; jb < 32; ++jb) {
    float4 e4[8];
    #pragma unroll
    for (int r = 0; r < 8; ++r) e4[r] = emb4[(k0 + r) * 32 + jb];
    #pragma unroll
    for (int i = 0; i < 4; ++i) {
      float4 va = voc4[(size_t)vidx[i] * 32 + jb];
      #pragma unroll
      for (int r = 0; r < 8; ++r)
        acc[i][r] += va.x * e4[r].x + va.y * e4[r].y + va.z * e4[r].z + va.w * e4[r].w;
    }
  }

  float sume[8];
  #pragma unroll
  for (int r = 0; r < 8; ++r) sume[r] = 0.f;
  #pragma unroll
  for (int i = 0; i < 4; ++i) {
    int vv = vbase + i;
    if (vv < V) {
      #pragma unroll
      for (int r = 0; r < 8; ++r) sume[r] += __expf(acc[i][r]);   // |logit| <~ 40 : safe
      uint4 st;
      st.x = bfpack(acc[i][0], acc[i][1]);
      st.y = bfpack(acc[i][2], acc[i][3]);
      st.z = bfpack(acc[i][4], acc[i][5]);
      st.w = bfpack(acc[i][6], acc[i][7]);
      *((uint4*)(qtbl + (size_t)vv * 64) + kt) = st;
    }
  }
  #pragma unroll
  for (int r = 0; r < 8; ++r) atomicAdd(&S_part[k0 + r], sume[r]);
  __syncthreads();
  if (tid < 128) atomicAdd(&S_glob[tid], S_part[tid]);
}

// ---------- K2c: in-place q[v][k] = exp(emis - Emax_v) (bf16), Emax table ----------
__global__ __launch_bounds__(256) void k_qtab(uint* __restrict__ qtbl,
    const float* __restrict__ S_glob, float* __restrict__ Emax, int V) {
  int tid = threadIdx.x;
  int l = tid & 63;
  int v = blockIdx.x * 4 + (tid >> 6);
  if (v >= V) return;
  float2 S2 = ((const float2*)S_glob)[l];
  float z0 = __logf(S2.x), z1 = __logf(S2.y);
  size_t off = (size_t)v * 64 + l;
  uint d = qtbl[off];
  float e0 = bflo(d) - z0, e1 = bfhi(d) - z1;
  float m = fmaxf(e0, e1);
  #pragma unroll
  for (int s = 1; s < 64; s <<= 1) m = fmaxf(m, __shfl_xor(m, s, 64));
  float q0 = __expf(e0 - m), q1 = __expf(e1 - m);
  qtbl[off] = bfpack(q0, q1);
  if (l == 0) Emax[v] = m;
}

// ---------- K3: sequential scan. ONE wave per chain, zero memory on critical path. ----------
// Lane l holds output columns 2l,2l+1 of T (128 dwords in VGPRs) and the packed state
// u(2l,2l+1) in one VGPR. u broadcast via v_readlane. No LDS, no barriers.
// amdgpu_waves_per_eu(1,1): caps the scheduler's occupancy target at 1 wave/EU so the
// register-pressure heuristic allows ~512 VGPRs -> table stays resident (the R3/R5
// failure was the default-occupancy pressure target forcing spills at ~88 VGPRs).

#define RL(j) ((uint)__builtin_amdgcn_readlane((int)ud, (j)))

#if HAVE_BFDOT
#define DOT4(i) { \
  uint u_0 = RL(4*(i)), u_1 = RL(4*(i)+1), u_2 = RL(4*(i)+2), u_3 = RL(4*(i)+3); \
  A0 = dot2bf(u_0, ta##i.x, A0); B0 = dot2bf(u_0, tb##i.x, B0); \
  A1 = dot2bf(u_1, ta##i.y, A1); B1 = dot2bf(u_1, tb##i.y, B1); \
  A2 = dot2bf(u_2, ta##i.z, A2); B2 = dot2bf(u_2, tb##i.z, B2); \
  A3 = dot2bf(u_3, ta##i.w, A3); B3 = dot2bf(u_3, tb##i.w, B3); }
#else
#define DOT4(i) { \
  uint u_0 = RL(4*(i)), u_1 = RL(4*(i)+1), u_2 = RL(4*(i)+2), u_3 = RL(4*(i)+3); \
  A0 = fmaf(bflo(u_0), bflo(ta##i.x), A0); A0 = fmaf(bfhi(u_0), bfhi(ta##i.x), A0); \
  B0 = fmaf(bflo(u_0), bflo(tb##i.x), B0); B0 = fmaf(bfhi(u_0), bfhi(tb##i.x), B0); \
  A1 = fmaf(bflo(u_1), bflo(ta##i.y), A1); A1 = fmaf(bfhi(u_1), bfhi(ta##i.y), A1); \
  B1 = fmaf(bflo(u_1), bflo(tb##i.y), B1); B1 = fmaf(bfhi(u_1), bfhi(tb##i.y), B1); \
  A2 = fmaf(bflo(u_2), bflo(ta##i.z), A2); A2 = fmaf(bfhi(u_2), bfhi(ta##i.z), A2); \
  B2 = fmaf(bflo(u_2), bflo(tb##i.z), B2); B2 = fmaf(bfhi(u_2), bfhi(tb##i.z), B2); \
  A3 = fmaf(bflo(u_3), bflo(ta##i.w), A3); A3 = fmaf(bfhi(u_3), bfhi(ta##i.w), A3); \
  B3 = fmaf(bflo(u_3), bflo(tb##i.w), B3); B3 = fmaf(bfhi(u_3), bfhi(tb##i.w), B3); }
#endif

#define REP16(M) M(0) M(1) M(2) M(3) M(4) M(5) M(6) M(7) \
                 M(8) M(9) M(10) M(11) M(12) M(13) M(14) M(15)

#define DECL_T(i) uint4 ta##i, tb##i;
#define LOAD_T(i) ta##i = ca[i]; tb##i = cb[i];
// Pin: kills global-load rematerialization.
#define PIN_T(i)  asm volatile("" : "+v"(ta##i.x), "+v"(ta##i.y), "+v"(ta##i.z), "+v"(ta##i.w)); \
                  asm volatile("" : "+v"(tb##i.x), "+v"(tb##i.y), "+v"(tb##i.z), "+v"(tb##i.w));

#define STEP(j) { \
  float A0 = 0.f, A1 = 0.f, A2 = 0.f, A3 = 0.f; \
  float B0 = 0.f, B1 = 0.f, B2 = 0.f, B3 = 0.f; \
  REP16(DOT4) \
  float s0 = (A0 + A1) + (A2 + A3); \
  float s1 = (B0 + B1) + (B2 + B3); \
  float nu0 = s0 * bflo(qc##j), nu1 = s1 * bfhi(qc##j); \
  { int tok = xrow[(tbase + (j) + 8) & 4095]; qc##j = qtbl[(size_t)tok * 64 + l]; } \
  if ((j) == 7) {                                 /* exact renorm every 8 steps */ \
    float tt = nu0 + nu1; \
    for (int s = 1; s < 64; s <<= 1) tt += __shfl_xor(tt, s, 64); \
    LLacc += __logf(tt); \
    float it = 1.0f / tt; nu0 *= it; nu1 *= it; \
  } \
  ud = bfpack(nu0, nu1); }

__global__ __attribute__((amdgpu_flat_work_group_size(64, 64), amdgpu_waves_per_eu(1, 1)))
void k_chain(const int* __restrict__ x,
    const float* __restrict__ start_w, const float* __restrict__ start_b,
    const uint* __restrict__ Tcol, const uint* __restrict__ qtbl,
    float* __restrict__ chainLL) {
  int n = blockIdx.x, l = threadIdx.x;
  const int* xrow = x + (size_t)n * 4096;

  // full table fragment: columns 2l, 2l+1, all 64 input pairs
  const uint4* ca = (const uint4*)(Tcol + (2 * l) * 64);
  const uint4* cb = (const uint4*)(Tcol + (2 * l + 1) * 64);
  REP16(DECL_T)
  REP16(LOAD_T)
  REP16(PIN_T)

  // init: u0 = softmax(start_w + start_b), LL0 = LSE(alpha0)
  float a0i = start_w[2 * l] + start_b[2 * l];
  float a1i = start_w[2 * l + 1] + start_b[2 * l + 1];
  float m = fmaxf(a0i, a1i);
  #pragma unroll
  for (int s = 1; s < 64; s <<= 1) m = fmaxf(m, __shfl_xor(m, s, 64));
  float p0 = __expf(a0i - m), p1 = __expf(a1i - m);
  float tot = p0 + p1;
  #pragma unroll
  for (int s = 1; s < 64; s <<= 1) tot += __shfl_xor(tot, s, 64);
  float LLacc = m + __logf(tot);
  float inv = 1.0f / tot;
  uint ud = bfpack(p0 * inv, p1 * inv);           // packed u(2l,2l+1)

  uint qc0 = qtbl[(size_t)xrow[0] * 64 + l], qc1 = qtbl[(size_t)xrow[1] * 64 + l];
  uint qc2 = qtbl[(size_t)xrow[2] * 64 + l], qc3 = qtbl[(size_t)xrow[3] * 64 + l];
  uint qc4 = qtbl[(size_t)xrow[4] * 64 + l], qc5 = qtbl[(size_t)xrow[5] * 64 + l];
  uint qc6 = qtbl[(size_t)xrow[6] * 64 + l], qc7 = qtbl[(size_t)xrow[7] * 64 + l];

  for (int t8 = 0; t8 < 512; ++t8) {
    int tbase = t8 * 8;
    STEP(0) STEP(1) STEP(2) STEP(3) STEP(4) STEP(5) STEP(6) STEP(7)
  }
  if (l == 0) chainLL[n] = LLacc;
}

// ---------- K4a: sum of Emax over all tokens ----------
__global__ __launch_bounds__(256) void k_emaxsum(const int* __restrict__ x,
    const float* __restrict__ Emax, float* __restrict__ sumE, int NT) {
  int idx = blockIdx.x * 256 + threadIdx.x;
  float s = 0.f;
  for (; idx < NT; idx += 128 * 256) s += Emax[x[idx]];
  #pragma unroll
  for (int mk = 1; mk < 64; mk <<= 1) s += __shfl_xor(s, mk, 64);
  if ((threadIdx.x & 63) == 0) atomicAdd(sumE, s);
}

// ---------- K4b: final scalar ----------
__global__ void k_final(const float* __restrict__ chainLL, const float* __restrict__ sumE,
                        float* __restrict__ out, int N) {
  int l = threadIdx.x;
  float v = (l < N) ? chainLL[l] : 0.f;
  #pragma unroll
  for (int mk = 1; mk < 64; mk <<= 1) v += __shfl_xor(v, mk, 64);
  if (l == 0) out[0] = -(v + sumE[0]) / (float)N;
}

extern "C" void kernel_launch(void* const* d_in, const int* in_sizes, int n_in,
                              void* d_out, int out_size, void* d_ws, size_t ws_size,
                              hipStream_t stream) {
  if (n_in < 6) return;
  const int*   x       = (const int*)d_in[0];
  const float* start_w = (const float*)d_in[1];
  const float* start_b = (const float*)d_in[2];
  const float* trans_w = (const float*)d_in[3];
  const float* emb_w   = (const float*)d_in[4];
  const float* vocab_w = (const float*)d_in[5];
  int NT = in_sizes[0];
  int N  = NT / 4096;
  int V  = in_sizes[5] / 128;

  char* ws = (char*)d_ws;
  float* S_glob  = (float*)(ws + 0);        // 128 f
  float* sumE    = (float*)(ws + 512);      // 1 f
  float* chainLL = (float*)(ws + 768);      // N f
  uint*  Tcol    = (uint*)(ws + 1024);      // 128*64 dwords = 32 KB
  float* Emax    = (float*)(ws + 36864);    // V floats
  uint*  qtbl    = (uint*)(ws + 262144);    // V*64 dwords = 12.8 MB

  hipMemsetAsync(d_ws, 0, 1024, stream);
  k_tran<<<dim3(1), dim3(128), 0, stream>>>(trans_w, Tcol);
  k_logits<<<dim3((V + 63) / 64), dim3(256), 0, stream>>>(emb_w, vocab_w, qtbl, S_glob, V);
  k_qtab<<<dim3((V + 3) / 4), dim3(256), 0, stream>>>(qtbl, S_glob, Emax, V);
  k_chain<<<dim3(N), dim3(64), 0, stream>>>(x, start_w, start_b, Tcol, qtbl, chainLL);
  k_emaxsum<<<dim3(128), dim3(256), 0, stream>>>(x, Emax, sumE, NT);
  k_final<<<dim3(1), dim3(64), 0, stream>>>(chainLL, sumE, (float*)d_out, N);
}